// Round 1
// baseline (624.365 us; speedup 1.0000x reference)
//
#include <hip/hip_runtime.h>
#include <math.h>

typedef unsigned short u16;
typedef __bf16 bf16;
typedef bf16 bf16x8 __attribute__((ext_vector_type(8)));
typedef float f32x4 __attribute__((ext_vector_type(4)));

#define DEV __device__ __forceinline__

DEV u16 f2b(float f) {
  unsigned u = __builtin_bit_cast(unsigned, f);
  u += 0x7fffu + ((u >> 16) & 1u);
  return (u16)(u >> 16);
}
DEV float b2f(u16 h) {
  unsigned u = ((unsigned)h) << 16;
  return __builtin_bit_cast(float, u);
}
DEV float gelu_f(float x) { return 0.5f * x * (1.0f + erff(x * 0.70710678118654752f)); }

DEV void gl2lds16(const void* g, void* l) {
  __builtin_amdgcn_global_load_lds(
      (const __attribute__((address_space(1))) unsigned int*)g,
      (__attribute__((address_space(3))) unsigned int*)l, 16, 0, 0);
}

// ---------------- weight transpose + fp32->bf16 ----------------
// src [R][C] f32 -> dst [C][R] bf16
__global__ void k_transpose_cvt(const float* __restrict__ src, u16* __restrict__ dst,
                                int R, int C) {
  __shared__ float tile[32][33];
  const int c0 = blockIdx.x * 32, r0 = blockIdx.y * 32;
  const int tx = threadIdx.x, ty = threadIdx.y;  // 32 x 8
#pragma unroll
  for (int i = 0; i < 32; i += 8)
    tile[ty + i][tx] = src[(long)(r0 + ty + i) * C + c0 + tx];
  __syncthreads();
#pragma unroll
  for (int i = 0; i < 32; i += 8)
    dst[(long)(c0 + ty + i) * R + r0 + tx] = f2b(tile[tx][ty + i]);
}

// ---------------- FiLM scale/shift: ss[b][j] = cond[b] . fw[:,j] + fb[j] ----------------
__global__ __launch_bounds__(256) void k_film_ss(const float* __restrict__ cond,
                                                 const float* __restrict__ fw,
                                                 const float* __restrict__ fb,
                                                 float* __restrict__ ss) {
  const int j = blockIdx.x * 256 + threadIdx.x;  // 0..2047
  const int b = blockIdx.y;
  const float* cp = cond + b * 1024;
  float acc = fb[j];
  for (int d = 0; d < 1024; ++d) acc = fmaf(cp[d], fw[d * 2048 + j], acc);
  ss[b * 2048 + j] = acc;
}

// ---------------- fused RMSNorm + FiLM, fp32 in -> bf16 out ----------------
__global__ __launch_bounds__(256) void k_rmsfilm(const float* __restrict__ x,
                                                 const float* __restrict__ nw,
                                                 const float* __restrict__ ss,
                                                 u16* __restrict__ h) {
  const int row = blockIdx.x;  // 0..8191
  const int b = row >> 11;
  const int t = threadIdx.x;
  const float4 v = ((const float4*)(x + (long)row * 1024))[t];
  float s = v.x * v.x + v.y * v.y + v.z * v.z + v.w * v.w;
#pragma unroll
  for (int off = 32; off; off >>= 1) s += __shfl_xor(s, off);
  __shared__ float red[4];
  const int wv = t >> 6, lane = t & 63;
  if (lane == 0) red[wv] = s;
  __syncthreads();
  const float tot = red[0] + red[1] + red[2] + red[3];
  const float rn = rsqrtf(tot * (1.0f / 1024.0f) + 1e-6f);
  const float4 w4 = ((const float4*)nw)[t];
  const float4 sc = ((const float4*)(ss + b * 2048))[t];
  const float4 sh = ((const float4*)(ss + b * 2048 + 1024))[t];
  ushort4 o;
  o.x = f2b(v.x * rn * w4.x * (1.0f + sc.x) + sh.x);
  o.y = f2b(v.y * rn * w4.y * (1.0f + sc.y) + sh.y);
  o.z = f2b(v.z * rn * w4.z * (1.0f + sc.z) + sh.z);
  o.w = f2b(v.w * rn * w4.w * (1.0f + sc.w) + sh.w);
  ((ushort4*)(h + (long)row * 1024))[t] = o;
}

// ---------------- row softmax over 2048 bf16, in place ----------------
__global__ __launch_bounds__(256) void k_softmax(u16* __restrict__ S) {
  u16* p = S + ((long)blockIdx.x << 11);
  const int t = threadIdx.x;
  ushort4 u0 = ((ushort4*)p)[2 * t], u1 = ((ushort4*)p)[2 * t + 1];
  float f[8] = {b2f(u0.x), b2f(u0.y), b2f(u0.z), b2f(u0.w),
                b2f(u1.x), b2f(u1.y), b2f(u1.z), b2f(u1.w)};
  float m = f[0];
#pragma unroll
  for (int i = 1; i < 8; ++i) m = fmaxf(m, f[i]);
#pragma unroll
  for (int off = 32; off; off >>= 1) m = fmaxf(m, __shfl_xor(m, off));
  __shared__ float red[4];
  const int wv = t >> 6, lane = t & 63;
  if (lane == 0) red[wv] = m;
  __syncthreads();
  m = fmaxf(fmaxf(red[0], red[1]), fmaxf(red[2], red[3]));
  float s = 0.0f;
#pragma unroll
  for (int i = 0; i < 8; ++i) {
    f[i] = __expf(f[i] - m);
    s += f[i];
  }
#pragma unroll
  for (int off = 32; off; off >>= 1) s += __shfl_xor(s, off);
  __syncthreads();
  if (lane == 0) red[wv] = s;
  __syncthreads();
  const float inv = 1.0f / (red[0] + red[1] + red[2] + red[3]);
  ushort4 o0, o1;
  o0.x = f2b(f[0] * inv); o0.y = f2b(f[1] * inv);
  o0.z = f2b(f[2] * inv); o0.w = f2b(f[3] * inv);
  o1.x = f2b(f[4] * inv); o1.y = f2b(f[5] * inv);
  o1.z = f2b(f[6] * inv); o1.w = f2b(f[7] * inv);
  ((ushort4*)p)[2 * t] = o0;
  ((ushort4*)p)[2 * t + 1] = o1;
}

// ---------------- bf16 MFMA GEMM: C = A[M,K] @ Bt[N,K]^T (+epilogue) ----------------
enum { EB = 1, ES = 2, EG = 4, ER = 8, EV = 16 };

template <int EPI, typename OutT>
__global__ __launch_bounds__(256, 2) void k_gemm(
    const u16* __restrict__ A, const u16* __restrict__ B, OutT* __restrict__ C,
    const float* __restrict__ bias, const float* __restrict__ resid, float scale,
    int N, int K, long sAb, long sBb, long sCb) {
  __shared__ u16 As[128 * 32];
  __shared__ u16 Bs[128 * 32];
  const int tid = threadIdx.x, lane = tid & 63, wv = tid >> 6;
  const int wr = wv >> 1, wc = wv & 1;
  const int r = lane & 15, q = lane >> 4;
  const long bm = (long)blockIdx.y * 128, bn = (long)blockIdx.x * 128;
  const u16* Ab = A + (long)blockIdx.z * sAb + bm * K;
  const u16* Bb = B + (long)blockIdx.z * sBb + bn * K;
  const int c0 = wv * 64 + lane;  // staging chunk ids c0, c0+256

  f32x4 acc[4][4] = {};

  for (int k0 = 0; k0 < K; k0 += 32) {
#pragma unroll
    for (int i = 0; i < 2; ++i) {
      const int c = c0 + i * 256;
      const long go = (long)(c >> 2) * K + k0 + (c & 3) * 8;
      gl2lds16(Ab + go, As + (i * 256 + wv * 64) * 8);
      gl2lds16(Bb + go, Bs + (i * 256 + wv * 64) * 8);
    }
    __syncthreads();
    bf16x8 af[4], bfr[4];
#pragma unroll
    for (int i = 0; i < 4; ++i) {
      af[i] = *(const bf16x8*)&As[(wr * 64 + i * 16 + r) * 32 + q * 8];
      bfr[i] = *(const bf16x8*)&Bs[(wc * 64 + i * 16 + r) * 32 + q * 8];
    }
#pragma unroll
    for (int mi = 0; mi < 4; ++mi)
#pragma unroll
      for (int ni = 0; ni < 4; ++ni)
        acc[mi][ni] = __builtin_amdgcn_mfma_f32_16x16x32_bf16(af[mi], bfr[ni], acc[mi][ni], 0, 0, 0);
    __syncthreads();
  }

  const long cb = (long)blockIdx.z * sCb;
#pragma unroll
  for (int ni = 0; ni < 4; ++ni) {
    const long col = bn + wc * 64 + ni * 16 + r;
    const float bv = (EPI & EB) ? bias[col] : 0.0f;
#pragma unroll
    for (int mi = 0; mi < 4; ++mi) {
#pragma unroll
      for (int j = 0; j < 4; ++j) {
        const long row = bm + wr * 64 + mi * 16 + q * 4 + j;
        float v = acc[mi][ni][j];
        if (EPI & ES) v *= scale;
        if (EPI & EB) v += bv;
        if (EPI & EG) v = gelu_f(v);
        if (EPI & ER) v += resid[row * N + col];
        if constexpr ((EPI & EV) != 0) {
          // transposed V store: Vt[b][d=col][n] ; batch = row>>11, n = row&2047
          const long bt = row >> 11, n = row & 2047;
          ((u16*)C)[(bt << 21) + (col << 11) + n] = f2b(v);
        } else if constexpr (sizeof(OutT) == 4) {
          C[cb + row * N + col] = v;
        } else {
          C[cb + row * N + col] = f2b(v);
        }
      }
    }
  }
}

extern "C" void kernel_launch(void* const* d_in, const int* in_sizes, int n_in,
                              void* d_out, int out_size, void* d_ws, size_t ws_size,
                              hipStream_t stream) {
  const float* x    = (const float*)d_in[0];
  const float* cond = (const float*)d_in[1];
  const float* n1w  = (const float*)d_in[2];
  const float* f1w  = (const float*)d_in[3];
  const float* f1b  = (const float*)d_in[4];
  const float* qw   = (const float*)d_in[5];
  const float* qb   = (const float*)d_in[6];
  const float* kw   = (const float*)d_in[7];
  const float* kb   = (const float*)d_in[8];
  const float* vw   = (const float*)d_in[9];
  const float* vb   = (const float*)d_in[10];
  const float* pw   = (const float*)d_in[11];
  const float* pb   = (const float*)d_in[12];
  const float* n2w  = (const float*)d_in[13];
  const float* f2w  = (const float*)d_in[14];
  const float* f2b_ = (const float*)d_in[15];
  const float* w1   = (const float*)d_in[16];
  const float* b1   = (const float*)d_in[17];
  const float* w2   = (const float*)d_in[18];
  const float* b2   = (const float*)d_in[19];
  float* out = (float*)d_out;

  char* ws = (char*)d_ws;
  size_t o = 0;
  auto alloc = [&](size_t bytes) {
    size_t ret = o;
    o += (bytes + 255) & ~(size_t)255;
    return ret;
  };
  const long N = 2048, D = 1024, H = 4096;

  u16* qT  = (u16*)(ws + alloc(D * D * 2));
  u16* kT  = (u16*)(ws + alloc(D * D * 2));
  u16* vT  = (u16*)(ws + alloc(D * D * 2));
  u16* pT  = (u16*)(ws + alloc(D * D * 2));
  u16* w1T = (u16*)(ws + alloc(D * H * 2));
  u16* w2T = (u16*)(ws + alloc(D * H * 2));
  float* ss1 = (float*)(ws + alloc(4 * 2 * D * 4));
  float* ss2 = (float*)(ws + alloc(4 * 2 * D * 4));
  u16* h   = (u16*)(ws + alloc(4 * N * D * 2));   // 16 MB
  float* x1 = (float*)(ws + alloc(4 * N * D * 4)); // 32 MB
  u16* AO  = (u16*)(ws + alloc(4 * N * D * 2));   // 16 MB
  const size_t big = o;                            // alias region
  u16* Q   = (u16*)(ws + alloc(4 * N * D * 2));
  u16* Kb  = (u16*)(ws + alloc(4 * N * D * 2));
  u16* Vt  = (u16*)(ws + alloc(4 * N * D * 2));
  u16* S   = (u16*)(ws + alloc(4 * N * N * 2));   // 32 MB
  u16* h1  = (u16*)(ws + big);                     // 64 MB, aliases Q..S
  (void)ws_size; (void)in_sizes; (void)n_in; (void)out_size;

  dim3 tb(32, 8);
  k_transpose_cvt<<<dim3(32, 32), tb, 0, stream>>>(qw, qT, 1024, 1024);
  k_transpose_cvt<<<dim3(32, 32), tb, 0, stream>>>(kw, kT, 1024, 1024);
  k_transpose_cvt<<<dim3(32, 32), tb, 0, stream>>>(vw, vT, 1024, 1024);
  k_transpose_cvt<<<dim3(32, 32), tb, 0, stream>>>(pw, pT, 1024, 1024);
  k_transpose_cvt<<<dim3(128, 32), tb, 0, stream>>>(w1, w1T, 1024, 4096);
  k_transpose_cvt<<<dim3(32, 128), tb, 0, stream>>>(w2, w2T, 4096, 1024);

  k_film_ss<<<dim3(8, 4), 256, 0, stream>>>(cond, f1w, f1b, ss1);
  k_film_ss<<<dim3(8, 4), 256, 0, stream>>>(cond, f2w, f2b_, ss2);

  k_rmsfilm<<<8192, 256, 0, stream>>>(x, n1w, ss1, h);

  // Q, K, V  (V stored transposed per batch)
  k_gemm<EB, u16><<<dim3(8, 64, 1), 256, 0, stream>>>(h, qT, Q, qb, nullptr, 1.0f, 1024, 1024, 0, 0, 0);
  k_gemm<EB, u16><<<dim3(8, 64, 1), 256, 0, stream>>>(h, kT, Kb, kb, nullptr, 1.0f, 1024, 1024, 0, 0, 0);
  k_gemm<EB | EV, u16><<<dim3(8, 64, 1), 256, 0, stream>>>(h, vT, Vt, vb, nullptr, 1.0f, 1024, 1024, 0, 0, 0);

  // S = Q @ K^T * D^-0.5   (batched)
  k_gemm<ES, u16><<<dim3(16, 16, 4), 256, 0, stream>>>(Q, Kb, S, nullptr, nullptr, 0.03125f,
                                                       2048, 1024, N * D, N * D, N * N);
  k_softmax<<<8192, 256, 0, stream>>>(S);

  // AO = P @ V   (batched; B-operand = Vt[d][n])
  k_gemm<0, u16><<<dim3(8, 16, 4), 256, 0, stream>>>(S, Vt, AO, nullptr, nullptr, 1.0f,
                                                     1024, 2048, N * N, D * N, N * D);

  // x1 = x + AO @ proj^T + pb
  k_gemm<EB | ER, float><<<dim3(8, 64, 1), 256, 0, stream>>>(AO, pT, x1, pb, x, 1.0f, 1024, 1024, 0, 0, 0);

  k_rmsfilm<<<8192, 256, 0, stream>>>(x1, n2w, ss2, h);

  // h1 = gelu(h @ w1 + b1)
  k_gemm<EB | EG, u16><<<dim3(32, 64, 1), 256, 0, stream>>>(h, w1T, h1, b1, nullptr, 1.0f, 4096, 1024, 0, 0, 0);

  // out = x1 + h1 @ w2 + b2
  k_gemm<EB | ER, float><<<dim3(8, 64, 1), 256, 0, stream>>>(h1, w2T, out, b2, x1, 1.0f, 1024, 4096, 0, 0, 0);
}